// Round 4
// baseline (193.758 us; speedup 1.0000x reference)
//
#include <hip/hip_runtime.h>

#define NB 32
#define NN 2048
#define NC 16
#define ND 128
#define NH 128
#define NK 384
#define TM 32
#define NBLK (NB * (NN / TM))   // 2048 blocks of 512 threads

typedef __bf16 bf16x8 __attribute__((ext_vector_type(8)));
typedef float f32x4 __attribute__((ext_vector_type(4)));

__device__ __forceinline__ unsigned short f2bf(float f){
  unsigned u = __float_as_uint(f);
  u = (u + 0x7fffu + ((u >> 16) & 1u)) >> 16;   // RNE
  return (unsigned short)u;
}
__device__ __forceinline__ unsigned enc_f32(float x){
  unsigned u = __float_as_uint(x);
  return (u & 0x80000000u) ? ~u : (u | 0x80000000u);
}
__device__ __forceinline__ float dec_f32(unsigned u){
  return __uint_as_float((u & 0x80000000u) ? (u & 0x7fffffffu) : ~u);
}

// swizzled LDS tile helpers (XOR bank swizzle: byte ^= (row&7)<<4)
__device__ __forceinline__ void stq(unsigned char* base, int stride, int row, int koff, uint4 u){
  *(uint4*)(base + row * stride + (koff ^ ((row & 7) << 4))) = u;
}
__device__ __forceinline__ void st8(unsigned char* base, int stride, int row, int koff, const float* f){
  uint4 u;
  u.x = (unsigned)f2bf(f[0]) | ((unsigned)f2bf(f[1]) << 16);
  u.y = (unsigned)f2bf(f[2]) | ((unsigned)f2bf(f[3]) << 16);
  u.z = (unsigned)f2bf(f[4]) | ((unsigned)f2bf(f[5]) << 16);
  u.w = (unsigned)f2bf(f[6]) | ((unsigned)f2bf(f[7]) << 16);
  stq(base, stride, row, koff, u);
}
__device__ __forceinline__ uint4 ldq(const unsigned char* base, int stride, int row, int koff){
  return *(const uint4*)(base + row * stride + (koff ^ ((row & 7) << 4)));
}

// ws layout
#define OFF_POOLED 0
#define OFF_W1     16384
#define OFF_W2     114688
#define OFF_DONE   147456
#define OFF_EMB    147712
#define WS_NEED_BF (OFF_EMB + (size_t)NB*NN*ND*2)

// ---- unified prep ----
// blocks [0,2048): nodeEmb f32 -> bf16, XCD-affine (chunk for batch b runs on b's XCD)
// blocks [2048,2072): W1 frags [cf][ks][lane]x16B ; pooled + done init
// blocks [2072,2080): W2 frags [cf][ks][lane]x16B
__global__ __launch_bounds__(256) void tbcnn_prep(
    const float* __restrict__ nodeEmb, const float* __restrict__ W1,
    const float* __restrict__ W2, unsigned* __restrict__ pooled,
    uint4* __restrict__ w1frag, uint4* __restrict__ w2frag,
    ushort* __restrict__ embBf, unsigned* __restrict__ done, int doEmb)
{
  const int blk = blockIdx.x;
  const int t = threadIdx.x;
  if (blk < 2048){
    if (!doEmb) return;
    // chunk chk covers float4 [chk*1024, chk*1024+1024) -> batch chk>>6 on XCD blk&7
    const int chk = ((blk & 7) << 8) | (blk >> 3);
    const float4* src = (const float4*)nodeEmb;
    #pragma unroll
    for (int it = 0; it < 4; ++it){
      const int i = chk * 1024 + it * 256 + t;
      float4 v = src[i];
      ushort4 o;
      o.x = f2bf(v.x); o.y = f2bf(v.y); o.z = f2bf(v.z); o.w = f2bf(v.w);
      *(ushort4*)(embBf + (size_t)i * 4) = o;
    }
  } else if (blk < 2072){
    const int tt = (blk - 2048) * 256 + t;        // 0..6143
    if (tt < NB * NH) pooled[tt] = 0u;            // enc-min
    if (tt == NB * NH) *done = 0u;
    const int lane = tt & 63;
    const int rest = tt >> 6;                     // 0..95
    const int ks = rest % 12;
    const int cf = rest / 12;
    const int col = (cf >> 1) * 32 + (cf & 1) * 16 + (lane & 15);
    const int k0 = ks * 32 + (lane >> 4) * 8;
    unsigned ps[4];
    #pragma unroll
    for (int p = 0; p < 4; ++p){
      unsigned lo = f2bf(W1[(size_t)(k0 + 2*p) * NH + col]);
      unsigned hi = f2bf(W1[(size_t)(k0 + 2*p + 1) * NH + col]);
      ps[p] = lo | (hi << 16);
    }
    w1frag[tt] = make_uint4(ps[0], ps[1], ps[2], ps[3]);
  } else {
    const int tt = (blk - 2072) * 256 + t;        // 0..2047
    const int lane = tt & 63;
    const int rest = tt >> 6;                     // 0..31
    const int ks = rest & 3;
    const int cf = rest >> 2;
    const int col = (cf >> 1) * 32 + (cf & 1) * 16 + (lane & 15);
    const int k0 = ks * 32 + (lane >> 4) * 8;
    unsigned ps[4];
    #pragma unroll
    for (int p = 0; p < 4; ++p){
      unsigned lo = f2bf(W2[(size_t)(k0 + 2*p) * NH + col]);
      unsigned hi = f2bf(W2[(size_t)(k0 + 2*p + 1) * NH + col]);
      ps[p] = lo | (hi << 16);
    }
    w2frag[tt] = make_uint4(ps[0], ps[1], ps[2], ps[3]);
  }
}

#define PROCU(u, i) { \
  float lo_ = __uint_as_float((u) << 16); \
  float hi_ = __uint_as_float((u) & 0xffff0000u); \
  aR[(i)]   += wrc * lo_; aL[(i)]   += wlc * lo_; \
  aR[(i)+1] += wrc * hi_; aL[(i)+1] += wlc * hi_; }

// ---- main: gather + wf (LDS) + MFMA + row-max + atomicMax + fused final ----
template<bool BF>
__global__ __launch_bounds__(512, 8) void tbcnn_main(
    const int* __restrict__ children, const float* __restrict__ nodeEmb,
    const ushort* __restrict__ embBf, const uint4* __restrict__ w1frag,
    const uint4* __restrict__ w2frag, const float* __restrict__ b1,
    const float* __restrict__ b2, unsigned* __restrict__ pooled,
    unsigned* __restrict__ done, float* __restrict__ out)
{
  __shared__ __align__(16) unsigned char wf_raw[TM * 768];   // 24 KB
  __shared__ unsigned last_flag;
  // XCD-aware swizzle: 2048 blocks = 8 XCDs x 256; each XCD owns 4 batches
  const int j0 = ((blockIdx.x & 7) << 8) | (blockIdx.x >> 3);
  const int b    = j0 >> 6;
  const int n0 = (j0 & 63) * TM;
  const int t = threadIdx.x;
  const int lane = t & 63;
  const int w = t >> 6;

  // ---- gather phase: 16 threads per node, 8 dims each ----
  {
    const int nloc = t >> 4;
    const int q = t & 15;
    const int d0 = q * 8;
    const int gn = n0 + nloc;
    const int4* chp4 = (const int4*)(children + ((size_t)b * NN + gn) * NC);

    int ns = 0;
    #pragma unroll
    for (int c4 = 0; c4 < 4; ++c4){
      int4 v = chp4[c4];
      ns += (v.x > 0) + (v.y > 0) + (v.z > 0) + (v.w > 0);
    }
    const float rdiv = 1.0f / (float)(((ns - 1) > 1) ? (ns - 1) : 1);
    const bool one_sib = (ns == 1);
    const size_t rowbase = (size_t)b * NN;

    // self -> k-block 0
    if (BF){
      const ushort* sp = embBf + (rowbase + gn) * ND + d0;
      stq(wf_raw, 768, nloc, 2 * d0, *(const uint4*)sp);
    } else {
      const float* sp = nodeEmb + (rowbase + gn) * ND + d0;
      float sv[8];
      float4 s0 = *(const float4*)sp;
      float4 s1 = *(const float4*)(sp + 4);
      sv[0]=s0.x; sv[1]=s0.y; sv[2]=s0.z; sv[3]=s0.w;
      sv[4]=s1.x; sv[5]=s1.y; sv[6]=s1.z; sv[7]=s1.w;
      st8(wf_raw, 768, nloc, 2 * d0, sv);
    }

    // children weighted sums
    float aR[8], aL[8];
    #pragma unroll
    for (int i = 0; i < 8; ++i){ aR[i] = 0.0f; aL[i] = 0.0f; }
    #pragma unroll
    for (int c4 = 0; c4 < 4; ++c4){
      int4 v = chp4[c4];                       // L1-hot reload, keeps regs low
      int cidx[4] = {v.x, v.y, v.z, v.w};
      #pragma unroll
      for (int jj = 0; jj < 4; ++jj){
        const int c = c4 * 4 + jj;
        const int idx = cidx[jj];
        const float mk  = (idx > 0) ? 1.0f : 0.0f;
        const float wrc = one_sib ? (0.5f * mk) : (mk * (float)c * rdiv);
        const float wlc = (1.0f - wrc) * mk;
        if (BF){
          uint4 u = *(const uint4*)(embBf + (rowbase + idx) * ND + d0);
          PROCU(u.x, 0) PROCU(u.y, 2) PROCU(u.z, 4) PROCU(u.w, 6)
        } else {
          const float* cp = nodeEmb + (rowbase + idx) * ND + d0;
          float4 u0 = *(const float4*)cp;
          float4 u1 = *(const float4*)(cp + 4);
          aR[0] += wrc * u0.x; aL[0] += wlc * u0.x;
          aR[1] += wrc * u0.y; aL[1] += wlc * u0.y;
          aR[2] += wrc * u0.z; aL[2] += wlc * u0.z;
          aR[3] += wrc * u0.w; aL[3] += wlc * u0.w;
          aR[4] += wrc * u1.x; aL[4] += wlc * u1.x;
          aR[5] += wrc * u1.y; aL[5] += wlc * u1.y;
          aR[6] += wrc * u1.z; aL[6] += wlc * u1.z;
          aR[7] += wrc * u1.w; aL[7] += wlc * u1.w;
        }
      }
    }
    st8(wf_raw, 768, nloc, 2 * (ND + d0),     aR);
    st8(wf_raw, 768, nloc, 2 * (2 * ND + d0), aL);
  }
  __syncthreads();

  // ---- MFMA: wave w owns cols [colbase, colbase+16), all 32 rows, K=384 ----
  {
    f32x4 acc0 = (f32x4){0.f,0.f,0.f,0.f};
    f32x4 acc1 = (f32x4){0.f,0.f,0.f,0.f};
    #pragma unroll 4
    for (int ks = 0; ks < 12; ++ks){
      bf16x8 B0 = __builtin_bit_cast(bf16x8, w1frag[(w * 12 + ks) * 64 + lane]);
      const int koff = ks * 64 + ((lane >> 4) << 4);
      bf16x8 a0 = __builtin_bit_cast(bf16x8, ldq(wf_raw, 768, (lane & 15),      koff));
      bf16x8 a1 = __builtin_bit_cast(bf16x8, ldq(wf_raw, 768, 16 + (lane & 15), koff));
      acc0 = __builtin_amdgcn_mfma_f32_16x16x32_bf16(a0, B0, acc0, 0, 0, 0);
      acc1 = __builtin_amdgcn_mfma_f32_16x16x32_bf16(a1, B0, acc1, 0, 0, 0);
    }
    float m = -3.0e38f;
    #pragma unroll
    for (int i = 0; i < 4; ++i){
      m = fmaxf(m, acc0[i]);
      m = fmaxf(m, acc1[i]);
    }
    m = fmaxf(m, __shfl_xor(m, 16, 64));
    m = fmaxf(m, __shfl_xor(m, 32, 64));
    const int colbase = (w >> 1) * 32 + (w & 1) * 16;
    if (lane < 16)
      atomicMax(pooled + b * NH + colbase + lane, enc_f32(m));
  }

  // ---- last-block ticket ----
  __syncthreads();                       // drains vmcnt: all this block's atomics visible
  if (t == 0){
    __threadfence();
    unsigned r = atomicAdd(done, 1u);
    last_flag = (r == NBLK - 1) ? 1u : 0u;
  }
  __syncthreads();
  if (!last_flag) return;

  // ---- fused final (last block only): h=tanh(pooled+b1) -> MFMA@W2 -> tanh -> cosine ----
  unsigned char* hls = wf_raw;                 // 32 x 128 bf16, swizzled, 8 KB
  float* os = (float*)(wf_raw + 8192);         // 32 x 128 f32, 16 KB
  if (t < 256){
    const int row = t >> 3;          // batch
    const int q = t & 7;
    const int d0 = q * 16;
    unsigned* pp = pooled + row * NH + d0;
    const float* bp = b1 + d0;
    float hv[16];
    #pragma unroll
    for (int j = 0; j < 16; ++j) hv[j] = tanhf(dec_f32(atomicMax(pp + j, 0u)) + bp[j]);
    st8(hls, 256, row, 2 * d0, hv);
    st8(hls, 256, row, 2 * (d0 + 8), hv + 8);
  }
  __syncthreads();
  if (t < 256){
    f32x4 acc[2][2];
    #pragma unroll
    for (int rf = 0; rf < 2; ++rf){
      acc[rf][0] = (f32x4){0.f,0.f,0.f,0.f};
      acc[rf][1] = (f32x4){0.f,0.f,0.f,0.f};
    }
    #pragma unroll
    for (int ks = 0; ks < 4; ++ks){
      bf16x8 B0 = __builtin_bit_cast(bf16x8, w2frag[((w * 2 + 0) * 4 + ks) * 64 + lane]);
      bf16x8 B1 = __builtin_bit_cast(bf16x8, w2frag[((w * 2 + 1) * 4 + ks) * 64 + lane]);
      const int koff = ks * 64 + ((lane >> 4) << 4);
      #pragma unroll
      for (int rf = 0; rf < 2; ++rf){
        bf16x8 a = __builtin_bit_cast(bf16x8, ldq(hls, 256, rf * 16 + (lane & 15), koff));
        acc[rf][0] = __builtin_amdgcn_mfma_f32_16x16x32_bf16(a, B0, acc[rf][0], 0, 0, 0);
        acc[rf][1] = __builtin_amdgcn_mfma_f32_16x16x32_bf16(a, B1, acc[rf][1], 0, 0, 0);
      }
    }
    #pragma unroll
    for (int rf = 0; rf < 2; ++rf)
      #pragma unroll
      for (int cf = 0; cf < 2; ++cf){
        const int col = w * 32 + cf * 16 + (lane & 15);
        const float bias = b2[col];
        #pragma unroll
        for (int i = 0; i < 4; ++i){
          const int r = rf * 16 + (lane >> 4) * 4 + i;
          os[r * NH + col] = tanhf(acc[rf][cf][i] + bias);
        }
      }
  }
  __syncthreads();
  if (t < 16){
    float s12 = 0.f, s11 = 0.f, s22 = 0.f;
    #pragma unroll 4
    for (int d = 0; d < NH; ++d){
      float a = os[t * NH + d];
      float c = os[(t + 16) * NH + d];
      s12 += a * c; s11 += a * a; s22 += c * c;
    }
    float n1 = fmaxf(sqrtf(s11), 1e-8f);
    float n2 = fmaxf(sqrtf(s22), 1e-8f);
    out[t] = s12 / (n1 * n2);
  }
}

extern "C" void kernel_launch(void* const* d_in, const int* in_sizes, int n_in,
                              void* d_out, int out_size, void* d_ws, size_t ws_size,
                              hipStream_t stream)
{
  const int*   children = (const int*)d_in[0];
  const float* nodeEmb  = (const float*)d_in[1];
  const float* W1       = (const float*)d_in[2];
  const float* b1       = (const float*)d_in[3];
  const float* W2       = (const float*)d_in[4];
  const float* b2       = (const float*)d_in[5];
  float* out = (float*)d_out;

  unsigned* pooled = (unsigned*)((char*)d_ws + OFF_POOLED);
  uint4* w1frag    = (uint4*)((char*)d_ws + OFF_W1);
  uint4* w2frag    = (uint4*)((char*)d_ws + OFF_W2);
  unsigned* done   = (unsigned*)((char*)d_ws + OFF_DONE);
  ushort* embBf    = (ushort*)((char*)d_ws + OFF_EMB);

  const bool bf = (ws_size >= WS_NEED_BF);

  tbcnn_prep<<<2080, 256, 0, stream>>>(nodeEmb, W1, W2, pooled, w1frag, w2frag, embBf, done, bf ? 1 : 0);
  if (bf)
    tbcnn_main<true><<<NBLK, 512, 0, stream>>>(children, nodeEmb, embBf, w1frag, w2frag, b1, b2, pooled, done, out);
  else
    tbcnn_main<false><<<NBLK, 512, 0, stream>>>(children, nodeEmb, embBf, w1frag, w2frag, b1, b2, pooled, done, out);
}

// Round 5
// 95.056 us; speedup vs baseline: 2.0384x; 2.0384x over previous
//
#include <hip/hip_runtime.h>

#define NB 32
#define NN 2048
#define NC 16
#define ND 128
#define NH 128
#define NK 384
#define TM 32
#define NBLK (NB * (NN / TM))   // 2048 blocks of 512 threads

typedef __bf16 bf16x8 __attribute__((ext_vector_type(8)));
typedef float f32x4 __attribute__((ext_vector_type(4)));

__device__ __forceinline__ unsigned short f2bf(float f){
  unsigned u = __float_as_uint(f);
  u = (u + 0x7fffu + ((u >> 16) & 1u)) >> 16;   // RNE
  return (unsigned short)u;
}
__device__ __forceinline__ unsigned enc_f32(float x){
  unsigned u = __float_as_uint(x);
  return (u & 0x80000000u) ? ~u : (u | 0x80000000u);
}
__device__ __forceinline__ float dec_f32(unsigned u){
  return __uint_as_float((u & 0x80000000u) ? (u & 0x7fffffffu) : ~u);
}

// swizzled LDS tile helpers (XOR bank swizzle: byte ^= (row&7)<<4)
__device__ __forceinline__ void stq(unsigned char* base, int stride, int row, int koff, uint4 u){
  *(uint4*)(base + row * stride + (koff ^ ((row & 7) << 4))) = u;
}
__device__ __forceinline__ void st8(unsigned char* base, int stride, int row, int koff, const float* f){
  uint4 u;
  u.x = (unsigned)f2bf(f[0]) | ((unsigned)f2bf(f[1]) << 16);
  u.y = (unsigned)f2bf(f[2]) | ((unsigned)f2bf(f[3]) << 16);
  u.z = (unsigned)f2bf(f[4]) | ((unsigned)f2bf(f[5]) << 16);
  u.w = (unsigned)f2bf(f[6]) | ((unsigned)f2bf(f[7]) << 16);
  stq(base, stride, row, koff, u);
}
__device__ __forceinline__ uint4 ldq(const unsigned char* base, int stride, int row, int koff){
  return *(const uint4*)(base + row * stride + (koff ^ ((row & 7) << 4)));
}

// ws layout
#define OFF_POOLED 0
#define OFF_W1     16384
#define OFF_W2     114688
#define OFF_DONE   147456
#define OFF_EMB    147712
#define WS_NEED_BF (OFF_EMB + (size_t)NB*NN*ND*2)

// ---- unified prep ----
// blocks [0,2048): nodeEmb f32 -> bf16, XCD-affine (chunk for batch b runs on b's XCD)
// blocks [2048,2072): W1 frags [cf][ks][lane]x16B ; pooled + done init
// blocks [2072,2080): W2 frags [cf][ks][lane]x16B
__global__ __launch_bounds__(256) void tbcnn_prep(
    const float* __restrict__ nodeEmb, const float* __restrict__ W1,
    const float* __restrict__ W2, unsigned* __restrict__ pooled,
    uint4* __restrict__ w1frag, uint4* __restrict__ w2frag,
    ushort* __restrict__ embBf, unsigned* __restrict__ done, int doEmb)
{
  const int blk = blockIdx.x;
  const int t = threadIdx.x;
  if (blk < 2048){
    if (!doEmb) return;
    // chunk chk covers float4 [chk*1024, chk*1024+1024) -> batch chk>>6 on XCD blk&7
    const int chk = ((blk & 7) << 8) | (blk >> 3);
    const float4* src = (const float4*)nodeEmb;
    #pragma unroll
    for (int it = 0; it < 4; ++it){
      const int i = chk * 1024 + it * 256 + t;
      float4 v = src[i];
      ushort4 o;
      o.x = f2bf(v.x); o.y = f2bf(v.y); o.z = f2bf(v.z); o.w = f2bf(v.w);
      *(ushort4*)(embBf + (size_t)i * 4) = o;
    }
  } else if (blk < 2072){
    const int tt = (blk - 2048) * 256 + t;        // 0..6143
    if (tt < NB * NH) pooled[tt] = 0u;            // enc-min
    if (tt == NB * NH) *done = 0u;
    const int lane = tt & 63;
    const int rest = tt >> 6;                     // 0..95
    const int ks = rest % 12;
    const int cf = rest / 12;
    const int col = (cf >> 1) * 32 + (cf & 1) * 16 + (lane & 15);
    const int k0 = ks * 32 + (lane >> 4) * 8;
    unsigned ps[4];
    #pragma unroll
    for (int p = 0; p < 4; ++p){
      unsigned lo = f2bf(W1[(size_t)(k0 + 2*p) * NH + col]);
      unsigned hi = f2bf(W1[(size_t)(k0 + 2*p + 1) * NH + col]);
      ps[p] = lo | (hi << 16);
    }
    w1frag[tt] = make_uint4(ps[0], ps[1], ps[2], ps[3]);
  } else {
    const int tt = (blk - 2072) * 256 + t;        // 0..2047
    const int lane = tt & 63;
    const int rest = tt >> 6;                     // 0..31
    const int ks = rest & 3;
    const int cf = rest >> 2;
    const int col = (cf >> 1) * 32 + (cf & 1) * 16 + (lane & 15);
    const int k0 = ks * 32 + (lane >> 4) * 8;
    unsigned ps[4];
    #pragma unroll
    for (int p = 0; p < 4; ++p){
      unsigned lo = f2bf(W2[(size_t)(k0 + 2*p) * NH + col]);
      unsigned hi = f2bf(W2[(size_t)(k0 + 2*p + 1) * NH + col]);
      ps[p] = lo | (hi << 16);
    }
    w2frag[tt] = make_uint4(ps[0], ps[1], ps[2], ps[3]);
  }
}

#define PROCU(u, i) { \
  float lo_ = __uint_as_float((u) << 16); \
  float hi_ = __uint_as_float((u) & 0xffff0000u); \
  aR[(i)]   += wrc * lo_; aL[(i)]   += wlc * lo_; \
  aR[(i)+1] += wrc * hi_; aL[(i)+1] += wlc * hi_; }

// ---- main: gather + wf (LDS) + MFMA + row-max + atomicMax + fused final ----
// launch_bounds(512,4): 128-VGPR cap. (512,8) forced 32 VGPRs -> 300MB scratch
// spill (R4, WRITE_SIZE counter); gather needs ~60 VGPRs. Keep cap >= 128.
template<bool BF>
__global__ __launch_bounds__(512, 4) void tbcnn_main(
    const int* __restrict__ children, const float* __restrict__ nodeEmb,
    const ushort* __restrict__ embBf, const uint4* __restrict__ w1frag,
    const uint4* __restrict__ w2frag, const float* __restrict__ b1,
    const float* __restrict__ b2, unsigned* __restrict__ pooled,
    unsigned* __restrict__ done, float* __restrict__ out)
{
  __shared__ __align__(16) unsigned char wf_raw[TM * 768];   // 24 KB
  __shared__ unsigned last_flag;
  // XCD-aware swizzle: 2048 blocks = 8 XCDs x 256; each XCD owns 4 batches
  const int j0 = ((blockIdx.x & 7) << 8) | (blockIdx.x >> 3);
  const int b    = j0 >> 6;
  const int n0 = (j0 & 63) * TM;
  const int t = threadIdx.x;
  const int lane = t & 63;
  const int w = t >> 6;

  // ---- gather phase: 16 threads per node, 8 dims each ----
  {
    const int nloc = t >> 4;
    const int q = t & 15;
    const int d0 = q * 8;
    const int gn = n0 + nloc;
    const int4* chp4 = (const int4*)(children + ((size_t)b * NN + gn) * NC);

    int ns = 0;
    #pragma unroll
    for (int c4 = 0; c4 < 4; ++c4){
      int4 v = chp4[c4];
      ns += (v.x > 0) + (v.y > 0) + (v.z > 0) + (v.w > 0);
    }
    const float rdiv = 1.0f / (float)(((ns - 1) > 1) ? (ns - 1) : 1);
    const bool one_sib = (ns == 1);
    const size_t rowbase = (size_t)b * NN;

    // self -> k-block 0
    if (BF){
      const ushort* sp = embBf + (rowbase + gn) * ND + d0;
      stq(wf_raw, 768, nloc, 2 * d0, *(const uint4*)sp);
    } else {
      const float* sp = nodeEmb + (rowbase + gn) * ND + d0;
      float sv[8];
      float4 s0 = *(const float4*)sp;
      float4 s1 = *(const float4*)(sp + 4);
      sv[0]=s0.x; sv[1]=s0.y; sv[2]=s0.z; sv[3]=s0.w;
      sv[4]=s1.x; sv[5]=s1.y; sv[6]=s1.z; sv[7]=s1.w;
      st8(wf_raw, 768, nloc, 2 * d0, sv);
    }

    // children weighted sums
    float aR[8], aL[8];
    #pragma unroll
    for (int i = 0; i < 8; ++i){ aR[i] = 0.0f; aL[i] = 0.0f; }
    #pragma unroll
    for (int c4 = 0; c4 < 4; ++c4){
      int4 v = chp4[c4];                       // L1-hot reload, keeps regs low
      int cidx[4] = {v.x, v.y, v.z, v.w};
      #pragma unroll
      for (int jj = 0; jj < 4; ++jj){
        const int c = c4 * 4 + jj;
        const int idx = cidx[jj];
        const float mk  = (idx > 0) ? 1.0f : 0.0f;
        const float wrc = one_sib ? (0.5f * mk) : (mk * (float)c * rdiv);
        const float wlc = (1.0f - wrc) * mk;
        if (BF){
          uint4 u = *(const uint4*)(embBf + (rowbase + idx) * ND + d0);
          PROCU(u.x, 0) PROCU(u.y, 2) PROCU(u.z, 4) PROCU(u.w, 6)
        } else {
          const float* cp = nodeEmb + (rowbase + idx) * ND + d0;
          float4 u0 = *(const float4*)cp;
          float4 u1 = *(const float4*)(cp + 4);
          aR[0] += wrc * u0.x; aL[0] += wlc * u0.x;
          aR[1] += wrc * u0.y; aL[1] += wlc * u0.y;
          aR[2] += wrc * u0.z; aL[2] += wlc * u0.z;
          aR[3] += wrc * u0.w; aL[3] += wlc * u0.w;
          aR[4] += wrc * u1.x; aL[4] += wlc * u1.x;
          aR[5] += wrc * u1.y; aL[5] += wlc * u1.y;
          aR[6] += wrc * u1.z; aL[6] += wlc * u1.z;
          aR[7] += wrc * u1.w; aL[7] += wlc * u1.w;
        }
      }
    }
    st8(wf_raw, 768, nloc, 2 * (ND + d0),     aR);
    st8(wf_raw, 768, nloc, 2 * (2 * ND + d0), aL);
  }
  __syncthreads();

  // ---- MFMA: wave w owns cols [colbase, colbase+16), all 32 rows, K=384 ----
  {
    f32x4 acc0 = (f32x4){0.f,0.f,0.f,0.f};
    f32x4 acc1 = (f32x4){0.f,0.f,0.f,0.f};
    #pragma unroll 4
    for (int ks = 0; ks < 12; ++ks){
      bf16x8 B0 = __builtin_bit_cast(bf16x8, w1frag[(w * 12 + ks) * 64 + lane]);
      const int koff = ks * 64 + ((lane >> 4) << 4);
      bf16x8 a0 = __builtin_bit_cast(bf16x8, ldq(wf_raw, 768, (lane & 15),      koff));
      bf16x8 a1 = __builtin_bit_cast(bf16x8, ldq(wf_raw, 768, 16 + (lane & 15), koff));
      acc0 = __builtin_amdgcn_mfma_f32_16x16x32_bf16(a0, B0, acc0, 0, 0, 0);
      acc1 = __builtin_amdgcn_mfma_f32_16x16x32_bf16(a1, B0, acc1, 0, 0, 0);
    }
    float m = -3.0e38f;
    #pragma unroll
    for (int i = 0; i < 4; ++i){
      m = fmaxf(m, acc0[i]);
      m = fmaxf(m, acc1[i]);
    }
    m = fmaxf(m, __shfl_xor(m, 16, 64));
    m = fmaxf(m, __shfl_xor(m, 32, 64));
    const int colbase = (w >> 1) * 32 + (w & 1) * 16;
    if (lane < 16)
      atomicMax(pooled + b * NH + colbase + lane, enc_f32(m));
  }

  // ---- last-block ticket ----
  __syncthreads();                       // all this block's atomics issued
  if (t == 0){
    __threadfence();
    unsigned r = atomicAdd(done, 1u);
    last_flag = (r == NBLK - 1) ? 1u : 0u;
  }
  __syncthreads();
  if (!last_flag) return;

  // ---- fused final (last block only): h=tanh(pooled+b1) -> MFMA@W2 -> tanh -> cosine ----
  unsigned char* hls = wf_raw;                 // 32 x 128 bf16, swizzled, 8 KB
  float* os = (float*)(wf_raw + 8192);         // 32 x 128 f32, 16 KB
  if (t < 256){
    const int row = t >> 3;          // batch
    const int q = t & 7;
    const int d0 = q * 16;
    unsigned* pp = pooled + row * NH + d0;
    const float* bp = b1 + d0;
    float hv[16];
    #pragma unroll
    for (int j = 0; j < 16; ++j) hv[j] = tanhf(dec_f32(atomicMax(pp + j, 0u)) + bp[j]);
    st8(hls, 256, row, 2 * d0, hv);
    st8(hls, 256, row, 2 * (d0 + 8), hv + 8);
  }
  __syncthreads();
  if (t < 256){
    f32x4 acc[2][2];
    #pragma unroll
    for (int rf = 0; rf < 2; ++rf){
      acc[rf][0] = (f32x4){0.f,0.f,0.f,0.f};
      acc[rf][1] = (f32x4){0.f,0.f,0.f,0.f};
    }
    #pragma unroll
    for (int ks = 0; ks < 4; ++ks){
      bf16x8 B0 = __builtin_bit_cast(bf16x8, w2frag[((w * 2 + 0) * 4 + ks) * 64 + lane]);
      bf16x8 B1 = __builtin_bit_cast(bf16x8, w2frag[((w * 2 + 1) * 4 + ks) * 64 + lane]);
      const int koff = ks * 64 + ((lane >> 4) << 4);
      #pragma unroll
      for (int rf = 0; rf < 2; ++rf){
        bf16x8 a = __builtin_bit_cast(bf16x8, ldq(hls, 256, rf * 16 + (lane & 15), koff));
        acc[rf][0] = __builtin_amdgcn_mfma_f32_16x16x32_bf16(a, B0, acc[rf][0], 0, 0, 0);
        acc[rf][1] = __builtin_amdgcn_mfma_f32_16x16x32_bf16(a, B1, acc[rf][1], 0, 0, 0);
      }
    }
    #pragma unroll
    for (int rf = 0; rf < 2; ++rf)
      #pragma unroll
      for (int cf = 0; cf < 2; ++cf){
        const int col = w * 32 + cf * 16 + (lane & 15);
        const float bias = b2[col];
        #pragma unroll
        for (int i = 0; i < 4; ++i){
          const int r = rf * 16 + (lane >> 4) * 4 + i;
          os[r * NH + col] = tanhf(acc[rf][cf][i] + bias);
        }
      }
  }
  __syncthreads();
  if (t < 16){
    float s12 = 0.f, s11 = 0.f, s22 = 0.f;
    #pragma unroll 4
    for (int d = 0; d < NH; ++d){
      float a = os[t * NH + d];
      float c = os[(t + 16) * NH + d];
      s12 += a * c; s11 += a * a; s22 += c * c;
    }
    float n1 = fmaxf(sqrtf(s11), 1e-8f);
    float n2 = fmaxf(sqrtf(s22), 1e-8f);
    out[t] = s12 / (n1 * n2);
  }
}

extern "C" void kernel_launch(void* const* d_in, const int* in_sizes, int n_in,
                              void* d_out, int out_size, void* d_ws, size_t ws_size,
                              hipStream_t stream)
{
  const int*   children = (const int*)d_in[0];
  const float* nodeEmb  = (const float*)d_in[1];
  const float* W1       = (const float*)d_in[2];
  const float* b1       = (const float*)d_in[3];
  const float* W2       = (const float*)d_in[4];
  const float* b2       = (const float*)d_in[5];
  float* out = (float*)d_out;

  unsigned* pooled = (unsigned*)((char*)d_ws + OFF_POOLED);
  uint4* w1frag    = (uint4*)((char*)d_ws + OFF_W1);
  uint4* w2frag    = (uint4*)((char*)d_ws + OFF_W2);
  unsigned* done   = (unsigned*)((char*)d_ws + OFF_DONE);
  ushort* embBf    = (ushort*)((char*)d_ws + OFF_EMB);

  const bool bf = (ws_size >= WS_NEED_BF);

  tbcnn_prep<<<2080, 256, 0, stream>>>(nodeEmb, W1, W2, pooled, w1frag, w2frag, embBf, done, bf ? 1 : 0);
  if (bf)
    tbcnn_main<true><<<NBLK, 512, 0, stream>>>(children, nodeEmb, embBf, w1frag, w2frag, b1, b2, pooled, done, out);
  else
    tbcnn_main<false><<<NBLK, 512, 0, stream>>>(children, nodeEmb, embBf, w1frag, w2frag, b1, b2, pooled, done, out);
}

// Round 6
// 57.108 us; speedup vs baseline: 3.3928x; 1.6645x over previous
//
#include <hip/hip_runtime.h>

#define NB 32
#define NN 2048
#define NC 16
#define ND 128
#define NH 128
#define NK 384
#define TM 32
#define NBLK (NB * (NN / TM))   // 2048 blocks of 256 threads

typedef __bf16 bf16x8 __attribute__((ext_vector_type(8)));
typedef float f32x4 __attribute__((ext_vector_type(4)));

__device__ __forceinline__ unsigned short f2bf(float f){
  unsigned u = __float_as_uint(f);
  u = (u + 0x7fffu + ((u >> 16) & 1u)) >> 16;   // RNE
  return (unsigned short)u;
}
__device__ __forceinline__ unsigned enc_f32(float x){
  unsigned u = __float_as_uint(x);
  return (u & 0x80000000u) ? ~u : (u | 0x80000000u);
}
__device__ __forceinline__ float dec_f32(unsigned u){
  return __uint_as_float((u & 0x80000000u) ? (u & 0x7fffffffu) : ~u);
}

// swizzled LDS tile helpers (XOR bank swizzle: byte ^= (row&7)<<4)
__device__ __forceinline__ void stq(unsigned char* base, int stride, int row, int koff, uint4 u){
  *(uint4*)(base + row * stride + (koff ^ ((row & 7) << 4))) = u;
}
__device__ __forceinline__ void st8(unsigned char* base, int stride, int row, int koff, const float* f){
  uint4 u;
  u.x = (unsigned)f2bf(f[0]) | ((unsigned)f2bf(f[1]) << 16);
  u.y = (unsigned)f2bf(f[2]) | ((unsigned)f2bf(f[3]) << 16);
  u.z = (unsigned)f2bf(f[4]) | ((unsigned)f2bf(f[5]) << 16);
  u.w = (unsigned)f2bf(f[6]) | ((unsigned)f2bf(f[7]) << 16);
  stq(base, stride, row, koff, u);
}
__device__ __forceinline__ uint4 ldq(const unsigned char* base, int stride, int row, int koff){
  return *(const uint4*)(base + row * stride + (koff ^ ((row & 7) << 4)));
}

// ws layout
#define OFF_POOLED 0
#define OFF_W1     16384
#define OFF_W2     114688
#define OFF_DONE   147456
#define OFF_EMB    147712
#define WS_NEED_BF (OFF_EMB + (size_t)NB*NN*ND*2)

// ---- unified prep ----
// blocks [0,2048): nodeEmb f32 -> bf16, XCD-affine (chunk for batch b runs on b's XCD)
// blocks [2048,2072): W1 frags [cf][ks][lane]x16B ; pooled + done init
// blocks [2072,2080): W2 frags [cf][ks][lane]x16B
__global__ __launch_bounds__(256) void tbcnn_prep(
    const float* __restrict__ nodeEmb, const float* __restrict__ W1,
    const float* __restrict__ W2, unsigned* __restrict__ pooled,
    uint4* __restrict__ w1frag, uint4* __restrict__ w2frag,
    ushort* __restrict__ embBf, unsigned* __restrict__ done, int doEmb)
{
  const int blk = blockIdx.x;
  const int t = threadIdx.x;
  if (blk < 2048){
    if (!doEmb) return;
    // chunk chk covers float4 [chk*1024, chk*1024+1024) -> batch chk>>6 on XCD blk&7
    const int chk = ((blk & 7) << 8) | (blk >> 3);
    const float4* src = (const float4*)nodeEmb;
    #pragma unroll
    for (int it = 0; it < 4; ++it){
      const int i = chk * 1024 + it * 256 + t;
      float4 v = src[i];
      ushort4 o;
      o.x = f2bf(v.x); o.y = f2bf(v.y); o.z = f2bf(v.z); o.w = f2bf(v.w);
      *(ushort4*)(embBf + (size_t)i * 4) = o;
    }
  } else if (blk < 2072){
    const int tt = (blk - 2048) * 256 + t;        // 0..6143
    if (tt < NB * NH) pooled[tt] = 0u;            // enc-min
    if (tt == NB * NH) *done = 0u;
    const int lane = tt & 63;
    const int rest = tt >> 6;                     // 0..95
    const int ks = rest % 12;
    const int cf = rest / 12;
    const int col = (cf >> 1) * 32 + (cf & 1) * 16 + (lane & 15);
    const int k0 = ks * 32 + (lane >> 4) * 8;
    unsigned ps[4];
    #pragma unroll
    for (int p = 0; p < 4; ++p){
      unsigned lo = f2bf(W1[(size_t)(k0 + 2*p) * NH + col]);
      unsigned hi = f2bf(W1[(size_t)(k0 + 2*p + 1) * NH + col]);
      ps[p] = lo | (hi << 16);
    }
    w1frag[tt] = make_uint4(ps[0], ps[1], ps[2], ps[3]);
  } else {
    const int tt = (blk - 2072) * 256 + t;        // 0..2047
    const int lane = tt & 63;
    const int rest = tt >> 6;                     // 0..31
    const int ks = rest & 3;
    const int cf = rest >> 2;
    const int col = (cf >> 1) * 32 + (cf & 1) * 16 + (lane & 15);
    const int k0 = ks * 32 + (lane >> 4) * 8;
    unsigned ps[4];
    #pragma unroll
    for (int p = 0; p < 4; ++p){
      unsigned lo = f2bf(W2[(size_t)(k0 + 2*p) * NH + col]);
      unsigned hi = f2bf(W2[(size_t)(k0 + 2*p + 1) * NH + col]);
      ps[p] = lo | (hi << 16);
    }
    w2frag[tt] = make_uint4(ps[0], ps[1], ps[2], ps[3]);
  }
}

#define PROCU(u, i) { \
  float lo_ = __uint_as_float((u) << 16); \
  float hi_ = __uint_as_float((u) & 0xffff0000u); \
  aR[(i)]   += wrc * lo_; aL[(i)]   += wlc * lo_; \
  aR[(i)+1] += wrc * hi_; aL[(i)+1] += wlc * hi_; }

// ---- main: gather + wf (LDS) + MFMA + row-max + atomicMax + fused final ----
// R3-proven shape: 256 thr, TM=32, 8 thr/node, (256,2). NO forced occupancy
// (R2/R4: caps below ~64 VGPR -> 300MB scratch spill). NO __threadfence in the
// ticket (R5: per-block device fence demoted the L2-resident gather set; atomics
// are device-coherent and __syncthreads drains vmcnt before the ticket).
template<bool BF>
__global__ __launch_bounds__(256, 2) void tbcnn_main(
    const int* __restrict__ children, const float* __restrict__ nodeEmb,
    const ushort* __restrict__ embBf, const uint4* __restrict__ w1frag,
    const uint4* __restrict__ w2frag, const float* __restrict__ b1,
    const float* __restrict__ b2, unsigned* __restrict__ pooled,
    unsigned* __restrict__ done, float* __restrict__ out)
{
  __shared__ __align__(16) unsigned char wf_raw[TM * 768];   // 24 KB
  __shared__ unsigned last_flag;
  // XCD-aware swizzle: 2048 blocks = 8 XCDs x 256; each XCD owns 4 batches
  const int j0 = ((blockIdx.x & 7) << 8) | (blockIdx.x >> 3);
  const int b    = j0 >> 6;
  const int n0 = (j0 & 63) * TM;
  const int t = threadIdx.x;
  const int lane = t & 63;
  const int w = t >> 6;

  // ---- gather phase: 8 threads per node, 16 dims each ----
  {
    const int nloc = t >> 3;
    const int q = t & 7;
    const int d0 = q * 16;
    const int gn = n0 + nloc;
    const int4* chp4 = (const int4*)(children + ((size_t)b * NN + gn) * NC);

    int ns = 0;
    #pragma unroll
    for (int c4 = 0; c4 < 4; ++c4){
      int4 v = chp4[c4];
      ns += (v.x > 0) + (v.y > 0) + (v.z > 0) + (v.w > 0);
    }
    const float rdiv = 1.0f / (float)(((ns - 1) > 1) ? (ns - 1) : 1);
    const bool one_sib = (ns == 1);
    const size_t rowbase = (size_t)b * NN;

    // self -> k-block 0
    if (BF){
      const ushort* sp = embBf + (rowbase + gn) * ND + d0;
      stq(wf_raw, 768, nloc, 2 * d0,       *(const uint4*)sp);
      stq(wf_raw, 768, nloc, 2 * (d0 + 8), *(const uint4*)(sp + 8));
    } else {
      const float* sp = nodeEmb + (rowbase + gn) * ND + d0;
      float sv[16];
      #pragma unroll
      for (int j = 0; j < 4; ++j){
        float4 s = *(const float4*)(sp + j * 4);
        sv[j*4+0]=s.x; sv[j*4+1]=s.y; sv[j*4+2]=s.z; sv[j*4+3]=s.w;
      }
      st8(wf_raw, 768, nloc, 2 * d0, sv);
      st8(wf_raw, 768, nloc, 2 * (d0 + 8), sv + 8);
    }

    // children weighted sums
    float aR[16], aL[16];
    #pragma unroll
    for (int i = 0; i < 16; ++i){ aR[i] = 0.0f; aL[i] = 0.0f; }
    #pragma unroll
    for (int c4 = 0; c4 < 4; ++c4){
      int4 v = chp4[c4];                       // L1-hot reload, keeps regs low
      int cidx[4] = {v.x, v.y, v.z, v.w};
      #pragma unroll
      for (int jj = 0; jj < 4; ++jj){
        const int c = c4 * 4 + jj;
        const int idx = cidx[jj];
        const float mk  = (idx > 0) ? 1.0f : 0.0f;
        const float wrc = one_sib ? (0.5f * mk) : (mk * (float)c * rdiv);
        const float wlc = (1.0f - wrc) * mk;
        if (BF){
          const ushort* cp = embBf + (rowbase + idx) * ND + d0;
          uint4 u0 = *(const uint4*)cp;
          uint4 u1 = *(const uint4*)(cp + 8);
          PROCU(u0.x, 0)  PROCU(u0.y, 2)  PROCU(u0.z, 4)  PROCU(u0.w, 6)
          PROCU(u1.x, 8)  PROCU(u1.y, 10) PROCU(u1.z, 12) PROCU(u1.w, 14)
        } else {
          const float* cp = nodeEmb + (rowbase + idx) * ND + d0;
          #pragma unroll
          for (int j = 0; j < 4; ++j){
            float4 u = *(const float4*)(cp + j * 4);
            aR[j*4+0] += wrc * u.x; aL[j*4+0] += wlc * u.x;
            aR[j*4+1] += wrc * u.y; aL[j*4+1] += wlc * u.y;
            aR[j*4+2] += wrc * u.z; aL[j*4+2] += wlc * u.z;
            aR[j*4+3] += wrc * u.w; aL[j*4+3] += wlc * u.w;
          }
        }
      }
    }
    st8(wf_raw, 768, nloc, 2 * (ND + d0),         aR);
    st8(wf_raw, 768, nloc, 2 * (ND + d0 + 8),     aR + 8);
    st8(wf_raw, 768, nloc, 2 * (2 * ND + d0),     aL);
    st8(wf_raw, 768, nloc, 2 * (2 * ND + d0 + 8), aL + 8);
  }
  __syncthreads();

  // ---- MFMA: 32 rows x 32 cols per wave, K=384; B frags streamed (L2-hot) ----
  {
    f32x4 acc[2][2];
    #pragma unroll
    for (int rf = 0; rf < 2; ++rf){
      acc[rf][0] = (f32x4){0.f, 0.f, 0.f, 0.f};
      acc[rf][1] = (f32x4){0.f, 0.f, 0.f, 0.f};
    }
    #pragma unroll 4
    for (int ks = 0; ks < 12; ++ks){
      bf16x8 B0 = __builtin_bit_cast(bf16x8, w1frag[((w * 2 + 0) * 12 + ks) * 64 + lane]);
      bf16x8 B1 = __builtin_bit_cast(bf16x8, w1frag[((w * 2 + 1) * 12 + ks) * 64 + lane]);
      const int koff = ks * 64 + ((lane >> 4) << 4);
      #pragma unroll
      for (int rf = 0; rf < 2; ++rf){
        const int row = rf * 16 + (lane & 15);
        bf16x8 a = __builtin_bit_cast(bf16x8, ldq(wf_raw, 768, row, koff));
        acc[rf][0] = __builtin_amdgcn_mfma_f32_16x16x32_bf16(a, B0, acc[rf][0], 0, 0, 0);
        acc[rf][1] = __builtin_amdgcn_mfma_f32_16x16x32_bf16(a, B1, acc[rf][1], 0, 0, 0);
      }
    }

    float m0 = -3.0e38f, m1 = -3.0e38f;
    #pragma unroll
    for (int rf = 0; rf < 2; ++rf)
      #pragma unroll
      for (int i = 0; i < 4; ++i){
        m0 = fmaxf(m0, acc[rf][0][i]);
        m1 = fmaxf(m1, acc[rf][1][i]);
      }
    m0 = fmaxf(m0, __shfl_xor(m0, 16, 64));
    m0 = fmaxf(m0, __shfl_xor(m0, 32, 64));
    m1 = fmaxf(m1, __shfl_xor(m1, 16, 64));
    m1 = fmaxf(m1, __shfl_xor(m1, 32, 64));
    if (lane < 16){
      atomicMax(pooled + b * NH + w * 32 + lane,      enc_f32(m0));
      atomicMax(pooled + b * NH + w * 32 + 16 + lane, enc_f32(m1));
    }
  }

  // ---- last-block ticket (no fence: atomic->atomic via coherence point;
  //      __syncthreads drains each wave's vmcnt incl. the atomics) ----
  __syncthreads();
  if (t == 0){
    unsigned r = atomicAdd(done, 1u);
    last_flag = (r == NBLK - 1) ? 1u : 0u;
  }
  __syncthreads();
  if (!last_flag) return;

  // ---- fused final (last block only): h=tanh(pooled+b1) -> MFMA@W2 -> tanh -> cosine ----
  unsigned char* hls = wf_raw;                 // 32 x 128 bf16, swizzled, 8 KB
  float* os = (float*)(wf_raw + 8192);         // 32 x 128 f32, 16 KB
  {
    const int row = t >> 3;          // batch
    const int q = t & 7;
    const int d0 = q * 16;
    unsigned* pp = pooled + row * NH + d0;
    const float* bp = b1 + d0;
    float hv[16];
    #pragma unroll
    for (int j = 0; j < 16; ++j) hv[j] = tanhf(dec_f32(atomicMax(pp + j, 0u)) + bp[j]);
    st8(hls, 256, row, 2 * d0, hv);
    st8(hls, 256, row, 2 * (d0 + 8), hv + 8);
  }
  __syncthreads();
  {
    f32x4 acc[2][2];
    #pragma unroll
    for (int rf = 0; rf < 2; ++rf){
      acc[rf][0] = (f32x4){0.f,0.f,0.f,0.f};
      acc[rf][1] = (f32x4){0.f,0.f,0.f,0.f};
    }
    #pragma unroll
    for (int ks = 0; ks < 4; ++ks){
      bf16x8 B0 = __builtin_bit_cast(bf16x8, w2frag[((w * 2 + 0) * 4 + ks) * 64 + lane]);
      bf16x8 B1 = __builtin_bit_cast(bf16x8, w2frag[((w * 2 + 1) * 4 + ks) * 64 + lane]);
      const int koff = ks * 64 + ((lane >> 4) << 4);
      #pragma unroll
      for (int rf = 0; rf < 2; ++rf){
        bf16x8 a = __builtin_bit_cast(bf16x8, ldq(hls, 256, rf * 16 + (lane & 15), koff));
        acc[rf][0] = __builtin_amdgcn_mfma_f32_16x16x32_bf16(a, B0, acc[rf][0], 0, 0, 0);
        acc[rf][1] = __builtin_amdgcn_mfma_f32_16x16x32_bf16(a, B1, acc[rf][1], 0, 0, 0);
      }
    }
    #pragma unroll
    for (int rf = 0; rf < 2; ++rf)
      #pragma unroll
      for (int cf = 0; cf < 2; ++cf){
        const int col = w * 32 + cf * 16 + (lane & 15);
        const float bias = b2[col];
        #pragma unroll
        for (int i = 0; i < 4; ++i){
          const int r = rf * 16 + (lane >> 4) * 4 + i;
          os[r * NH + col] = tanhf(acc[rf][cf][i] + bias);
        }
      }
  }
  __syncthreads();
  if (t < 16){
    float s12 = 0.f, s11 = 0.f, s22 = 0.f;
    #pragma unroll 4
    for (int d = 0; d < NH; ++d){
      float a = os[t * NH + d];
      float c = os[(t + 16) * NH + d];
      s12 += a * c; s11 += a * a; s22 += c * c;
    }
    float n1 = fmaxf(sqrtf(s11), 1e-8f);
    float n2 = fmaxf(sqrtf(s22), 1e-8f);
    out[t] = s12 / (n1 * n2);
  }
}

extern "C" void kernel_launch(void* const* d_in, const int* in_sizes, int n_in,
                              void* d_out, int out_size, void* d_ws, size_t ws_size,
                              hipStream_t stream)
{
  const int*   children = (const int*)d_in[0];
  const float* nodeEmb  = (const float*)d_in[1];
  const float* W1       = (const float*)d_in[2];
  const float* b1       = (const float*)d_in[3];
  const float* W2       = (const float*)d_in[4];
  const float* b2       = (const float*)d_in[5];
  float* out = (float*)d_out;

  unsigned* pooled = (unsigned*)((char*)d_ws + OFF_POOLED);
  uint4* w1frag    = (uint4*)((char*)d_ws + OFF_W1);
  uint4* w2frag    = (uint4*)((char*)d_ws + OFF_W2);
  unsigned* done   = (unsigned*)((char*)d_ws + OFF_DONE);
  ushort* embBf    = (ushort*)((char*)d_ws + OFF_EMB);

  const bool bf = (ws_size >= WS_NEED_BF);

  tbcnn_prep<<<2080, 256, 0, stream>>>(nodeEmb, W1, W2, pooled, w1frag, w2frag, embBf, done, bf ? 1 : 0);
  if (bf)
    tbcnn_main<true><<<NBLK, 256, 0, stream>>>(children, nodeEmb, embBf, w1frag, w2frag, b1, b2, pooled, done, out);
  else
    tbcnn_main<false><<<NBLK, 256, 0, stream>>>(children, nodeEmb, embBf, w1frag, w2frag, b1, b2, pooled, done, out);
}